// Round 4
// baseline (654.260 us; speedup 1.0000x reference)
//
#include <hip/hip_runtime.h>
#include <stdint.h>

#define B_ 8
#define T_ 4096
#define D_ 1024
#define H_ 1024
#define M_ (B_*T_)   /* 32768 */
#define K_ D_
#define N_ H_
#define TC2 64
#define NC2 (T_/TC2) /* 64 */

typedef short short8 __attribute__((ext_vector_type(8)));
typedef float f32x4 __attribute__((ext_vector_type(4)));
typedef unsigned short ushort8v __attribute__((ext_vector_type(8)));

__device__ __forceinline__ float bf2f(unsigned short u) {
    union { unsigned int i; float f; } x; x.i = ((unsigned int)u) << 16; return x.f;
}
__device__ __forceinline__ unsigned short f2bf(float f) {
    union { float f; unsigned int i; } x; x.f = f;
    unsigned int u = x.i;
    unsigned int r = u + 0x7fffu + ((u >> 16) & 1u);
    return (unsigned short)(r >> 16);
}
__device__ __forceinline__ void gld_lds16(const unsigned short* g, unsigned short* l) {
    __builtin_amdgcn_global_load_lds(
        (const __attribute__((address_space(1))) void*)(const void*)g,
        (__attribute__((address_space(3))) void*)(void*)l, 16, 0, 0);
}
__device__ __forceinline__ float gfun(float x) {
    return x >= 0.f ? x + 0.5f : 1.f / (1.f + __expf(-x));
}

// ---------------- fp32 -> bf16 convert ----------------
__global__ void cvt_kernel(const float* __restrict__ src, unsigned short* __restrict__ dst, int n4) {
    int i = blockIdx.x * blockDim.x + threadIdx.x;
    const int stride = gridDim.x * blockDim.x;
    for (; i < n4; i += stride) {
        float4 v = ((const float4*)src)[i];
        ushort4 o;
        o.x = f2bf(v.x); o.y = f2bf(v.y); o.z = f2bf(v.z); o.w = f2bf(v.w);
        ((ushort4*)dst)[i] = o;
    }
}

// both weight matrices in one launch (blockIdx.y selects)
__global__ void cvtw_kernel(const float* __restrict__ Wz, const float* __restrict__ Wh,
                            unsigned short* __restrict__ wzb, unsigned short* __restrict__ whb, int n4) {
    const float* src = blockIdx.y ? Wh : Wz;
    unsigned short* dst = blockIdx.y ? whb : wzb;
    int i = blockIdx.x * blockDim.x + threadIdx.x;
    const int stride = gridDim.x * blockDim.x;
    for (; i < n4; i += stride) {
        float4 v = ((const float4*)src)[i];
        ushort4 o;
        o.x = f2bf(v.x); o.y = f2bf(v.y); o.z = f2bf(v.z); o.w = f2bf(v.w);
        ((ushort4*)dst)[i] = o;
    }
}

// ---------------- flag clear (decoupled-lookback state) ----------------
__global__ void clear_kernel(int* __restrict__ flags, int n) {
    int i = blockIdx.x * blockDim.x + threadIdx.x;
    if (i < n) flags[i] = 0;
}

// ---------------- bf16 MFMA GEMM: 256x256 tile, 8-phase, persistent (R2 version) ----------
// LDS-BW-bound steady state (~142 us). Do not re-pipeline reads: R3's 12-fragment
// double-buffer spilled to scratch (WRITE_SIZE +17.9 MB) and regressed 1.6x.
#define SB() __builtin_amdgcn_sched_barrier(0)
#define BAR() do { SB(); __builtin_amdgcn_s_barrier(); SB(); } while (0)

__global__ __launch_bounds__(512, 2) void gemm_kernel(
    const unsigned short* __restrict__ Xb,
    const unsigned short* __restrict__ Wzb,
    const unsigned short* __restrict__ Whb,
    const float* __restrict__ bz, const float* __restrict__ bh,
    unsigned short* __restrict__ KzOut, unsigned short* __restrict__ KhOut)
{
    __shared__ __align__(16) unsigned short ldsA[2][256 * 64];
    __shared__ __align__(16) unsigned short ldsB[2][256 * 64];

    const int bx = blockIdx.x;      // row-supertile: rows [bx*1024, bx*1024+1024)
    const int bn = blockIdx.y;
    const int mat = blockIdx.z;
    const unsigned short* Wb = mat ? Whb : Wzb;
    const float* bias = mat ? bh : bz;
    unsigned short* Out = mat ? KhOut : KzOut;

    const int tid = threadIdx.x;
    const int w = tid >> 6, lane = tid & 63;
    const int wm = w >> 2, wn = w & 3;       // 2 x 4 wave grid; wave owns 128x64 of C

    // ---- staging addressing (inverse-swizzled global source) ----
    const int srow = lane >> 3;                       // row within 8-row wave group
    const int schunk = ((lane & 7) ^ srow) << 3;      // ushort offset of 16B chunk
    const unsigned short* gA = Xb + (size_t)(bx * 1024 + srow) * K_ + schunk;
    const unsigned short* gB = Wb + (size_t)(bn * 256 + srow) * K_ + schunk;

// global K-step g: A row-block = (g>>4)*256 within the supertile, kt = g&15
#define STAGE_A(s, g, h) do { \
    gld_lds16(gA + (size_t)(((g) >> 4) * 256 + (h)*128 + w*8) * K_ + ((g)&15) * 64, \
              &ldsA[s][((h)*128 + w*8) * 64]); \
    gld_lds16(gA + (size_t)(((g) >> 4) * 256 + (h)*128 + 64 + w*8) * K_ + ((g)&15) * 64, \
              &ldsA[s][((h)*128 + 64 + w*8) * 64]); \
  } while (0)
#define STAGE_B(s, g, h) do { \
    gld_lds16(gB + (size_t)((h)*128 + w*8) * K_ + ((g)&15) * 64, \
              &ldsB[s][((h)*128 + w*8) * 64]); \
    gld_lds16(gB + (size_t)((h)*128 + 64 + w*8) * K_ + ((g)&15) * 64, \
              &ldsB[s][((h)*128 + 64 + w*8) * 64]); \
  } while (0)

    // ---- fragment read addressing (swizzled) ----
    const int lrow = lane & 15;
    const int q = lane >> 4;
    const int sw0 = (q ^ (lane & 7)) << 3;   // ushort offset of kh=0 slot; kh=1 is ^32

#define LDA(s, fm, kh) (*(const short8*)&ldsA[s][(wm*128 + (fm)*16 + lrow) * 64 + (sw0 ^ ((kh)*32))])
#define LDB(s, fn, kh) (*(const short8*)&ldsB[s][(wn*64  + (fn)*16 + lrow) * 64 + (sw0 ^ ((kh)*32))])

#define RD_A4(s, fmb) do { \
    _Pragma("unroll") for (int f = 0; f < 4; ++f) { Ar[f][0] = LDA(s, (fmb)+f, 0); Ar[f][1] = LDA(s, (fmb)+f, 1); } \
  } while (0)
#define RD_B2(s, fnb) do { \
    _Pragma("unroll") for (int g2_ = 0; g2_ < 2; ++g2_) { Br[(fnb)+g2_][0] = LDB(s, (fnb)+g2_, 0); Br[(fnb)+g2_][1] = LDB(s, (fnb)+g2_, 1); } \
  } while (0)

#define QUAD(mb, nb) do { \
    __builtin_amdgcn_s_setprio(1); \
    _Pragma("unroll") for (int f = 0; f < 4; ++f) { \
      _Pragma("unroll") for (int g2_ = 0; g2_ < 2; ++g2_) { \
        acc[(mb)+f][(nb)+g2_] = __builtin_amdgcn_mfma_f32_16x16x32_bf16(Ar[f][0], Br[(nb)+g2_][0], acc[(mb)+f][(nb)+g2_], 0, 0, 0); \
        acc[(mb)+f][(nb)+g2_] = __builtin_amdgcn_mfma_f32_16x16x32_bf16(Ar[f][1], Br[(nb)+g2_][1], acc[(mb)+f][(nb)+g2_], 0, 0, 0); \
      } \
    } \
    __builtin_amdgcn_s_setprio(0); \
  } while (0)

    f32x4 acc[8][4];
    short8 Ar[4][2], Br[4][2];

    // bias values are t-invariant; hoist
    float bb[4];
#pragma unroll
    for (int fn = 0; fn < 4; ++fn) bb[fn] = bias[bn * 256 + wn * 64 + fn * 16 + lrow];

    // ---- prologue: g=0 (slot0, A+B all halves) + g=1 B halves ----
    STAGE_B(0, 0, 0); STAGE_B(0, 0, 1);
    STAGE_A(0, 0, 0); STAGE_A(0, 0, 1);
    STAGE_B(1, 1, 0); STAGE_B(1, 1, 1);
    SB();
    asm volatile("s_waitcnt vmcnt(4)" ::: "memory");   // g=0 landed; g=1 B in flight
    BAR();

#pragma unroll 1
    for (int t = 0; t < 4; ++t) {
#pragma unroll
        for (int i = 0; i < 8; ++i)
#pragma unroll
            for (int j = 0; j < 4; ++j) acc[i][j] = (f32x4){0.f, 0.f, 0.f, 0.f};

#pragma unroll 1
        for (int i = 0; i < 8; ++i) {
            const int g1 = t * 16 + 2 * i + 1;
            const int g2 = g1 + 1;
            const int g3 = g1 + 2;
            const bool st = (g2 < 64);   // false only at t=3,i=7

            // ---- P1: read slot0 A(m0-3)+B(n0-1); stage slot1 A-h0 (g1) ----
            RD_A4(0, 0); RD_B2(0, 0);
            STAGE_A(1, g1, 0);
            BAR();
            QUAD(0, 0);
            BAR();
            // ---- P2: read slot0 B(n2-3); stage slot1 A-h1 (g1) ----
            RD_B2(0, 2);
            STAGE_A(1, g1, 1);
            BAR();
            QUAD(0, 2);
            BAR();
            // ---- P3: read slot0 A(m4-7); stage slot0 B-h0 (g2) ----
            RD_A4(0, 4);
            if (st) STAGE_B(0, g2, 0);
            BAR();
            QUAD(4, 0);
            BAR();
            // ---- P4: stage slot0 B-h1 (g2); GATE: g1 landed before P5 ----
            if (st) {
                STAGE_B(0, g2, 1);
                SB();
                asm volatile("s_waitcnt vmcnt(4)" ::: "memory");
            } else {
                asm volatile("s_waitcnt vmcnt(0)" ::: "memory");   // final drain
            }
            BAR();
            QUAD(4, 2);
            BAR();
            // ---- P5: read slot1 A(m0-3)+B(n0-1); stage slot0 A-h0 (g2) ----
            RD_A4(1, 0); RD_B2(1, 0);
            if (st) STAGE_A(0, g2, 0);
            BAR();
            QUAD(0, 0);
            BAR();
            // ---- P6: read slot1 B(n2-3); stage slot0 A-h1 (g2) ----
            RD_B2(1, 2);
            if (st) STAGE_A(0, g2, 1);
            BAR();
            QUAD(0, 2);
            BAR();
            // ---- P7: read slot1 A(m4-7); stage slot1 B-h0 (g3) ----
            RD_A4(1, 4);
            if (st) STAGE_B(1, g3, 0);
            BAR();
            QUAD(4, 0);
            BAR();
            // ---- P8: stage slot1 B-h1 (g3); GATE: g2 (slot0) landed before next P1 ----
            if (st) {
                STAGE_B(1, g3, 1);
                SB();
                asm volatile("s_waitcnt vmcnt(4)" ::: "memory");
            }
            BAR();
            QUAD(4, 2);
            BAR();
        }

        // ---- per-tile epilogue (no LDS, runs under in-flight prefetch) ----
        // K[m][n] at ((m>>2)*N + n)*4 + (m&3); m = (bx*4+t)*256 + wm*128 + fm*16 + q*4 + r
#pragma unroll
        for (int fn = 0; fn < 4; ++fn) {
            const int n = bn * 256 + wn * 64 + fn * 16 + lrow;
#pragma unroll
            for (int fm = 0; fm < 8; ++fm) {
                const int mq = (bx * 4 + t) * 64 + wm * 32 + fm * 4 + q;
                ushort4 o;
                o.x = f2bf(acc[fm][fn][0] + bb[fn]);
                o.y = f2bf(acc[fm][fn][1] + bb[fn]);
                o.z = f2bf(acc[fm][fn][2] + bb[fn]);
                o.w = f2bf(acc[fm][fn][3] + bb[fn]);
                *(ushort4*)(Out + ((size_t)mq * N_ + n) * 4) = o;
            }
        }
    }
}

// Packed-layout accessor note:
// K[m][n] lives at ((m>>2)*N + n)*4 + (m&3), m = b*T + t.
// A thread owning columns hb..hb+3 loads, per t-quad, two 16B vectors:
//   base = ((b*1024 + (t0>>2))*N + hb)*4 ; v0 = cols hb,hb+1 ; v1 = cols hb+2,hb+3
//   value(col j, t0+r) = v[j>>1][(j&1)*4 + r]

// ---------------- fused single-pass scan: decoupled lookback ----------------
// 512 blocks (chunk c in [0,64), batch b) x 256 threads; 4 h-cols/thread.
// All 512 blocks co-resident (2 blocks/CU at 8 waves) -> spin-wait is
// dispatch-order-safe. Protocol per (b,c): pass-1 aggregate (F,V) over 64 t;
// publish AGG (flag=1, release/agent); lookback j=c-1..0 accumulating
// P = aF*state_j + aV until an INCLUSIVE (flag=2) or j<0 (use g(h0));
// publish inclusive state Incl_c = F*P+V (flag=2); pass-2 replay from P
// (kz/kh re-read hits Infinity Cache; 128 MB < 256 MB L3) writing Out.
__global__ __launch_bounds__(256) void scan_fused(
    const unsigned short* __restrict__ Kz, const unsigned short* __restrict__ Kh,
    const float* __restrict__ h0,
    float* __restrict__ FA, float* __restrict__ VA, float* __restrict__ Incl,
    int* flags, float* __restrict__ Out)
{
    const int c = blockIdx.x, b = blockIdx.y;
    const int hb = threadIdx.x * 4;
    __shared__ int sh_flag;

    // ---- pass 1: local aggregate ----
    float F[4] = {1.f, 1.f, 1.f, 1.f}, V[4] = {0.f, 0.f, 0.f, 0.f};
    const size_t base0 = ((size_t)(b * (T_ / 4) + c * (TC2 / 4)) * N_ + hb) * 4;
    size_t base = base0;
    for (int qq = 0; qq < TC2 / 4; qq++) {
        ushort8v z0 = *(const ushort8v*)(Kz + base);
        ushort8v z1 = *(const ushort8v*)(Kz + base + 8);
        ushort8v h0v = *(const ushort8v*)(Kh + base);
        ushort8v h1v = *(const ushort8v*)(Kh + base + 8);
        base += (size_t)N_ * 4;
#pragma unroll
        for (int r = 0; r < 4; r++) {
            float kzf[4] = {bf2f(z0[r]), bf2f(z0[4 + r]), bf2f(z1[r]), bf2f(z1[4 + r])};
            float khf[4] = {bf2f(h0v[r]), bf2f(h0v[4 + r]), bf2f(h1v[r]), bf2f(h1v[4 + r])};
#pragma unroll
            for (int j = 0; j < 4; j++) {
                float f = 1.f / (1.f + __expf(kzf[j]));   // 1 - sigmoid(kz)
                float v = (1.f - f) * gfun(khf[j]);       // sigmoid(kz)*g(kh)
                V[j] = f * V[j] + v;
                F[j] *= f;
            }
        }
    }

    // ---- publish aggregate ----
    const size_t oc = ((size_t)(b * NC2 + c)) * H_ + hb;
    *(float4*)(FA + oc) = make_float4(F[0], F[1], F[2], F[3]);
    *(float4*)(VA + oc) = make_float4(V[0], V[1], V[2], V[3]);
    __threadfence();
    __syncthreads();
    if (threadIdx.x == 0)
        __hip_atomic_store(&flags[b * NC2 + c], 1, __ATOMIC_RELEASE, __HIP_MEMORY_SCOPE_AGENT);

    // ---- lookback: P = state before chunk c ----
    float aF[4] = {1.f, 1.f, 1.f, 1.f}, aV[4] = {0.f, 0.f, 0.f, 0.f};
    float cy[4];
    bool done = false;
    int j = c - 1;
    while (!done && j >= 0) {
        if (threadIdx.x == 0) {
            int s;
            while ((s = __hip_atomic_load(&flags[b * NC2 + j], __ATOMIC_ACQUIRE,
                                          __HIP_MEMORY_SCOPE_AGENT)) == 0)
                __builtin_amdgcn_s_sleep(8);
            sh_flag = s;
        }
        __syncthreads();
        const int s = sh_flag;
        __syncthreads();
        const size_t oj = ((size_t)(b * NC2 + j)) * H_ + hb;
        if (s == 2) {
            float4 I = *(const float4*)(Incl + oj);
            cy[0] = aF[0] * I.x + aV[0];
            cy[1] = aF[1] * I.y + aV[1];
            cy[2] = aF[2] * I.z + aV[2];
            cy[3] = aF[3] * I.w + aV[3];
            done = true;
        } else {
            float4 fj = *(const float4*)(FA + oj);
            float4 vj = *(const float4*)(VA + oj);
            aV[0] = aF[0] * vj.x + aV[0];  aF[0] *= fj.x;
            aV[1] = aF[1] * vj.y + aV[1];  aF[1] *= fj.y;
            aV[2] = aF[2] * vj.z + aV[2];  aF[2] *= fj.z;
            aV[3] = aF[3] * vj.w + aV[3];  aF[3] *= fj.w;
            --j;
        }
    }
    if (!done) {
#pragma unroll
        for (int k = 0; k < 4; ++k)
            cy[k] = aF[k] * gfun(h0[(size_t)b * H_ + hb + k]) + aV[k];
    }

    // ---- publish inclusive state ----
    {
        float4 inc = make_float4(F[0] * cy[0] + V[0], F[1] * cy[1] + V[1],
                                 F[2] * cy[2] + V[2], F[3] * cy[3] + V[3]);
        *(float4*)(Incl + oc) = inc;
    }
    __threadfence();
    __syncthreads();
    if (threadIdx.x == 0)
        __hip_atomic_store(&flags[b * NC2 + c], 2, __ATOMIC_RELEASE, __HIP_MEMORY_SCOPE_AGENT);

    // ---- row 0 (t=0) from h0, written once ----
    if (c == 0) {
        float4 r0 = make_float4(gfun(h0[(size_t)b * H_ + hb + 0]), gfun(h0[(size_t)b * H_ + hb + 1]),
                                gfun(h0[(size_t)b * H_ + hb + 2]), gfun(h0[(size_t)b * H_ + hb + 3]));
        *(float4*)(Out + (size_t)b * (T_ + 1) * H_ + hb) = r0;
    }

    // ---- pass 2: replay with carry (reads hit L3) ----
    base = base0;
    size_t ob = ((size_t)(b * (T_ + 1) + c * TC2 + 1)) * H_ + hb;
    for (int qq = 0; qq < TC2 / 4; qq++) {
        ushort8v z0 = *(const ushort8v*)(Kz + base);
        ushort8v z1 = *(const ushort8v*)(Kz + base + 8);
        ushort8v h0v = *(const ushort8v*)(Kh + base);
        ushort8v h1v = *(const ushort8v*)(Kh + base + 8);
        base += (size_t)N_ * 4;
#pragma unroll
        for (int r = 0; r < 4; r++) {
            float kzf[4] = {bf2f(z0[r]), bf2f(z0[4 + r]), bf2f(z1[r]), bf2f(z1[4 + r])};
            float khf[4] = {bf2f(h0v[r]), bf2f(h0v[4 + r]), bf2f(h1v[r]), bf2f(h1v[4 + r])};
#pragma unroll
            for (int jj = 0; jj < 4; jj++) {
                float f = 1.f / (1.f + __expf(kzf[jj]));
                float v = (1.f - f) * gfun(khf[jj]);
                cy[jj] = f * cy[jj] + v;
            }
            *(float4*)(Out + ob) = make_float4(cy[0], cy[1], cy[2], cy[3]);
            ob += H_;
        }
    }
}

extern "C" void kernel_launch(void* const* d_in, const int* in_sizes, int n_in,
                              void* d_out, int out_size, void* d_ws, size_t ws_size,
                              hipStream_t stream)
{
    const float* x  = (const float*)d_in[0];
    const float* h0 = (const float*)d_in[1];
    const float* Wz = (const float*)d_in[2];
    const float* bz = (const float*)d_in[3];
    const float* Wh = (const float*)d_in[4];
    const float* bh = (const float*)d_in[5];
    float* out = (float*)d_out;

    char* ws = (char*)d_ws;
    unsigned short* xb  = (unsigned short*)ws; ws += (size_t)M_ * K_ * 2;   // 64 MiB
    unsigned short* wzb = (unsigned short*)ws; ws += (size_t)N_ * K_ * 2;   // 2 MiB
    unsigned short* whb = (unsigned short*)ws; ws += (size_t)N_ * K_ * 2;   // 2 MiB
    unsigned short* kz  = (unsigned short*)ws; ws += (size_t)M_ * N_ * 2;   // 64 MiB
    unsigned short* kh  = (unsigned short*)ws; ws += (size_t)M_ * N_ * 2;   // 64 MiB
    float* FA   = (float*)ws; ws += (size_t)B_ * NC2 * H_ * 4;              // 2 MiB
    float* VA   = (float*)ws; ws += (size_t)B_ * NC2 * H_ * 4;              // 2 MiB
    float* Incl = (float*)ws; ws += (size_t)B_ * NC2 * H_ * 4;              // 2 MiB
    int* flags  = (int*)ws;   ws += 4096;

    clear_kernel<<<1, 512, 0, stream>>>(flags, B_ * NC2);
    cvt_kernel<<<2048, 256, 0, stream>>>(x, xb, M_ * K_ / 4);
    cvtw_kernel<<<dim3(128, 2), 256, 0, stream>>>(Wz, Wh, wzb, whb, N_ * K_ / 4);

    dim3 gg(M_ / 1024, N_ / 256, 2);
    gemm_kernel<<<gg, 512, 0, stream>>>(xb, wzb, whb, bz, bh, kz, kh);

    scan_fused<<<dim3(NC2, B_), 256, 0, stream>>>(kz, kh, h0, FA, VA, Incl, flags, out);
}

// Round 5
// 445.304 us; speedup vs baseline: 1.4692x; 1.4692x over previous
//
#include <hip/hip_runtime.h>
#include <stdint.h>

#define B_ 8
#define T_ 4096
#define D_ 1024
#define H_ 1024
#define M_ (B_*T_)   /* 32768 */
#define K_ D_
#define N_ H_
#define TC 32
#define NC (T_/TC)   /* 128 */

typedef short short8 __attribute__((ext_vector_type(8)));
typedef float f32x4 __attribute__((ext_vector_type(4)));
typedef unsigned short ushort8v __attribute__((ext_vector_type(8)));

__device__ __forceinline__ float bf2f(unsigned short u) {
    union { unsigned int i; float f; } x; x.i = ((unsigned int)u) << 16; return x.f;
}
__device__ __forceinline__ unsigned short f2bf(float f) {
    union { float f; unsigned int i; } x; x.f = f;
    unsigned int u = x.i;
    unsigned int r = u + 0x7fffu + ((u >> 16) & 1u);
    return (unsigned short)(r >> 16);
}
__device__ __forceinline__ void gld_lds16(const unsigned short* g, unsigned short* l) {
    __builtin_amdgcn_global_load_lds(
        (const __attribute__((address_space(1))) void*)(const void*)g,
        (__attribute__((address_space(3))) void*)(void*)l, 16, 0, 0);
}
// sigmoid/gfun via raw v_rcp_f32 (1 instr) instead of IEEE divide chain (~10 instr).
// rel err ~1e-5: invisible vs bf16 inputs and 1.5e-2 tolerance.
__device__ __forceinline__ float sigm_neg(float k) {   // 1/(1+exp(k)) = 1 - sigmoid(k)
    return __builtin_amdgcn_rcpf(1.f + __expf(k));
}
__device__ __forceinline__ float gfun(float x) {       // x>=0: x+0.5 ; x<0: sigmoid(x)
    float neg = __builtin_amdgcn_rcpf(1.f + __expf(-x));
    return x >= 0.f ? x + 0.5f : neg;
}

// ---------------- fp32 -> bf16 convert ----------------
__global__ void cvt_kernel(const float* __restrict__ src, unsigned short* __restrict__ dst, int n4) {
    int i = blockIdx.x * blockDim.x + threadIdx.x;
    const int stride = gridDim.x * blockDim.x;
    for (; i < n4; i += stride) {
        float4 v = ((const float4*)src)[i];
        ushort4 o;
        o.x = f2bf(v.x); o.y = f2bf(v.y); o.z = f2bf(v.z); o.w = f2bf(v.w);
        ((ushort4*)dst)[i] = o;
    }
}

// both weight matrices in one launch (blockIdx.y selects)
__global__ void cvtw_kernel(const float* __restrict__ Wz, const float* __restrict__ Wh,
                            unsigned short* __restrict__ wzb, unsigned short* __restrict__ whb, int n4) {
    const float* src = blockIdx.y ? Wh : Wz;
    unsigned short* dst = blockIdx.y ? whb : wzb;
    int i = blockIdx.x * blockDim.x + threadIdx.x;
    const int stride = gridDim.x * blockDim.x;
    for (; i < n4; i += stride) {
        float4 v = ((const float4*)src)[i];
        ushort4 o;
        o.x = f2bf(v.x); o.y = f2bf(v.y); o.z = f2bf(v.z); o.w = f2bf(v.w);
        ((ushort4*)dst)[i] = o;
    }
}

// ---------------- bf16 MFMA GEMM: 256x256 tile, 8-phase, persistent (R2 version) ----------
// LDS-BW-bound steady state (~142 us). Do not re-pipeline reads: R3's 12-fragment
// double-buffer spilled to scratch (WRITE_SIZE +17.9 MB) and regressed 1.6x.
#define SB() __builtin_amdgcn_sched_barrier(0)
#define BAR() do { SB(); __builtin_amdgcn_s_barrier(); SB(); } while (0)

__global__ __launch_bounds__(512, 2) void gemm_kernel(
    const unsigned short* __restrict__ Xb,
    const unsigned short* __restrict__ Wzb,
    const unsigned short* __restrict__ Whb,
    const float* __restrict__ bz, const float* __restrict__ bh,
    unsigned short* __restrict__ KzOut, unsigned short* __restrict__ KhOut)
{
    __shared__ __align__(16) unsigned short ldsA[2][256 * 64];
    __shared__ __align__(16) unsigned short ldsB[2][256 * 64];

    const int bx = blockIdx.x;      // row-supertile: rows [bx*1024, bx*1024+1024)
    const int bn = blockIdx.y;
    const int mat = blockIdx.z;
    const unsigned short* Wb = mat ? Whb : Wzb;
    const float* bias = mat ? bh : bz;
    unsigned short* Out = mat ? KhOut : KzOut;

    const int tid = threadIdx.x;
    const int w = tid >> 6, lane = tid & 63;
    const int wm = w >> 2, wn = w & 3;       // 2 x 4 wave grid; wave owns 128x64 of C

    // ---- staging addressing (inverse-swizzled global source) ----
    const int srow = lane >> 3;                       // row within 8-row wave group
    const int schunk = ((lane & 7) ^ srow) << 3;      // ushort offset of 16B chunk
    const unsigned short* gA = Xb + (size_t)(bx * 1024 + srow) * K_ + schunk;
    const unsigned short* gB = Wb + (size_t)(bn * 256 + srow) * K_ + schunk;

// global K-step g: A row-block = (g>>4)*256 within the supertile, kt = g&15
#define STAGE_A(s, g, h) do { \
    gld_lds16(gA + (size_t)(((g) >> 4) * 256 + (h)*128 + w*8) * K_ + ((g)&15) * 64, \
              &ldsA[s][((h)*128 + w*8) * 64]); \
    gld_lds16(gA + (size_t)(((g) >> 4) * 256 + (h)*128 + 64 + w*8) * K_ + ((g)&15) * 64, \
              &ldsA[s][((h)*128 + 64 + w*8) * 64]); \
  } while (0)
#define STAGE_B(s, g, h) do { \
    gld_lds16(gB + (size_t)((h)*128 + w*8) * K_ + ((g)&15) * 64, \
              &ldsB[s][((h)*128 + w*8) * 64]); \
    gld_lds16(gB + (size_t)((h)*128 + 64 + w*8) * K_ + ((g)&15) * 64, \
              &ldsB[s][((h)*128 + 64 + w*8) * 64]); \
  } while (0)

    // ---- fragment read addressing (swizzled) ----
    const int lrow = lane & 15;
    const int q = lane >> 4;
    const int sw0 = (q ^ (lane & 7)) << 3;   // ushort offset of kh=0 slot; kh=1 is ^32

#define LDA(s, fm, kh) (*(const short8*)&ldsA[s][(wm*128 + (fm)*16 + lrow) * 64 + (sw0 ^ ((kh)*32))])
#define LDB(s, fn, kh) (*(const short8*)&ldsB[s][(wn*64  + (fn)*16 + lrow) * 64 + (sw0 ^ ((kh)*32))])

#define RD_A4(s, fmb) do { \
    _Pragma("unroll") for (int f = 0; f < 4; ++f) { Ar[f][0] = LDA(s, (fmb)+f, 0); Ar[f][1] = LDA(s, (fmb)+f, 1); } \
  } while (0)
#define RD_B2(s, fnb) do { \
    _Pragma("unroll") for (int g2_ = 0; g2_ < 2; ++g2_) { Br[(fnb)+g2_][0] = LDB(s, (fnb)+g2_, 0); Br[(fnb)+g2_][1] = LDB(s, (fnb)+g2_, 1); } \
  } while (0)

#define QUAD(mb, nb) do { \
    __builtin_amdgcn_s_setprio(1); \
    _Pragma("unroll") for (int f = 0; f < 4; ++f) { \
      _Pragma("unroll") for (int g2_ = 0; g2_ < 2; ++g2_) { \
        acc[(mb)+f][(nb)+g2_] = __builtin_amdgcn_mfma_f32_16x16x32_bf16(Ar[f][0], Br[(nb)+g2_][0], acc[(mb)+f][(nb)+g2_], 0, 0, 0); \
        acc[(mb)+f][(nb)+g2_] = __builtin_amdgcn_mfma_f32_16x16x32_bf16(Ar[f][1], Br[(nb)+g2_][1], acc[(mb)+f][(nb)+g2_], 0, 0, 0); \
      } \
    } \
    __builtin_amdgcn_s_setprio(0); \
  } while (0)

    f32x4 acc[8][4];
    short8 Ar[4][2], Br[4][2];

    // bias values are t-invariant; hoist
    float bb[4];
#pragma unroll
    for (int fn = 0; fn < 4; ++fn) bb[fn] = bias[bn * 256 + wn * 64 + fn * 16 + lrow];

    // ---- prologue: g=0 (slot0, A+B all halves) + g=1 B halves ----
    STAGE_B(0, 0, 0); STAGE_B(0, 0, 1);
    STAGE_A(0, 0, 0); STAGE_A(0, 0, 1);
    STAGE_B(1, 1, 0); STAGE_B(1, 1, 1);
    SB();
    asm volatile("s_waitcnt vmcnt(4)" ::: "memory");   // g=0 landed; g=1 B in flight
    BAR();

#pragma unroll 1
    for (int t = 0; t < 4; ++t) {
#pragma unroll
        for (int i = 0; i < 8; ++i)
#pragma unroll
            for (int j = 0; j < 4; ++j) acc[i][j] = (f32x4){0.f, 0.f, 0.f, 0.f};

#pragma unroll 1
        for (int i = 0; i < 8; ++i) {
            const int g1 = t * 16 + 2 * i + 1;
            const int g2 = g1 + 1;
            const int g3 = g1 + 2;
            const bool st = (g2 < 64);   // false only at t=3,i=7

            // ---- P1: read slot0 A(m0-3)+B(n0-1); stage slot1 A-h0 (g1) ----
            RD_A4(0, 0); RD_B2(0, 0);
            STAGE_A(1, g1, 0);
            BAR();
            QUAD(0, 0);
            BAR();
            // ---- P2: read slot0 B(n2-3); stage slot1 A-h1 (g1) ----
            RD_B2(0, 2);
            STAGE_A(1, g1, 1);
            BAR();
            QUAD(0, 2);
            BAR();
            // ---- P3: read slot0 A(m4-7); stage slot0 B-h0 (g2) ----
            RD_A4(0, 4);
            if (st) STAGE_B(0, g2, 0);
            BAR();
            QUAD(4, 0);
            BAR();
            // ---- P4: stage slot0 B-h1 (g2); GATE: g1 landed before P5 ----
            if (st) {
                STAGE_B(0, g2, 1);
                SB();
                asm volatile("s_waitcnt vmcnt(4)" ::: "memory");
            } else {
                asm volatile("s_waitcnt vmcnt(0)" ::: "memory");   // final drain
            }
            BAR();
            QUAD(4, 2);
            BAR();
            // ---- P5: read slot1 A(m0-3)+B(n0-1); stage slot0 A-h0 (g2) ----
            RD_A4(1, 0); RD_B2(1, 0);
            if (st) STAGE_A(0, g2, 0);
            BAR();
            QUAD(0, 0);
            BAR();
            // ---- P6: read slot1 B(n2-3); stage slot0 A-h1 (g2) ----
            RD_B2(1, 2);
            if (st) STAGE_A(0, g2, 1);
            BAR();
            QUAD(0, 2);
            BAR();
            // ---- P7: read slot1 A(m4-7); stage slot1 B-h0 (g3) ----
            RD_A4(1, 4);
            if (st) STAGE_B(1, g3, 0);
            BAR();
            QUAD(4, 0);
            BAR();
            // ---- P8: stage slot1 B-h1 (g3); GATE: g2 (slot0) landed before next P1 ----
            if (st) {
                STAGE_B(1, g3, 1);
                SB();
                asm volatile("s_waitcnt vmcnt(4)" ::: "memory");
            }
            BAR();
            QUAD(4, 2);
            BAR();
        }

        // ---- per-tile epilogue (no LDS, runs under in-flight prefetch) ----
        // K[m][n] at ((m>>2)*N + n)*4 + (m&3); m = (bx*4+t)*256 + wm*128 + fm*16 + q*4 + r
#pragma unroll
        for (int fn = 0; fn < 4; ++fn) {
            const int n = bn * 256 + wn * 64 + fn * 16 + lrow;
#pragma unroll
            for (int fm = 0; fm < 8; ++fm) {
                const int mq = (bx * 4 + t) * 64 + wm * 32 + fm * 4 + q;
                ushort4 o;
                o.x = f2bf(acc[fm][fn][0] + bb[fn]);
                o.y = f2bf(acc[fm][fn][1] + bb[fn]);
                o.z = f2bf(acc[fm][fn][2] + bb[fn]);
                o.w = f2bf(acc[fm][fn][3] + bb[fn]);
                *(ushort4*)(Out + ((size_t)mq * N_ + n) * 4) = o;
            }
        }
    }
}

// Packed-layout accessor note for scans:
// K[m][n] lives at ((m>>2)*N + n)*4 + (m&3), m = b*T + t.
// A thread owning columns hb..hb+3 loads, per t-quad q, two 16B vectors:
//   base = ((b*1024 + (t0>>2))*N + hb)*4 ; v0 = cols hb,hb+1 ; v1 = cols hb+2,hb+3
//   value(col j, t0+r) = v[j>>1][(j&1)*4 + r]

// per-t-quad math, shared by scanA/scanC
#define QUAD_MATH(CYSTMT)                                                              \
    _Pragma("unroll")                                                                  \
    for (int r = 0; r < 4; r++) {                                                      \
        float kzf[4] = {bf2f(z0[r]), bf2f(z0[4 + r]), bf2f(z1[r]), bf2f(z1[4 + r])};   \
        float khf[4] = {bf2f(h0v[r]), bf2f(h0v[4 + r]), bf2f(h1v[r]), bf2f(h1v[4 + r])};\
        _Pragma("unroll")                                                              \
        for (int j = 0; j < 4; j++) {                                                  \
            float f = sigm_neg(kzf[j]);            /* 1 - sigmoid(kz) */               \
            float v = (1.f - f) * gfun(khf[j]);    /* sigmoid(kz)*g(kh) */             \
            CYSTMT                                                                     \
        }                                                                              \
    }

// ---------------- scan A: per-chunk affine aggregates (F = prod f, V) ----------------
// register-prefetched: next q-iter's 4 vectors load while current math runs
__global__ __launch_bounds__(256) void scanA_kernel(const unsigned short* __restrict__ Kz,
                                                    const unsigned short* __restrict__ Kh,
                                                    float* __restrict__ Fc, float* __restrict__ Vc)
{
    const int c = blockIdx.x, b = blockIdx.y;
    const int hb = threadIdx.x * 4;
    float F[4] = {1.f, 1.f, 1.f, 1.f}, V[4] = {0.f, 0.f, 0.f, 0.f};
    size_t base = ((size_t)(b * (T_ / 4) + c * (TC / 4)) * N_ + hb) * 4;
    ushort8v z0 = *(const ushort8v*)(Kz + base);
    ushort8v z1 = *(const ushort8v*)(Kz + base + 8);
    ushort8v h0v = *(const ushort8v*)(Kh + base);
    ushort8v h1v = *(const ushort8v*)(Kh + base + 8);
#pragma unroll 1
    for (int qq = 0; qq < TC / 4; qq++) {
        ushort8v nz0, nz1, nh0, nh1;
        if (qq + 1 < TC / 4) {
            const size_t nb = base + (size_t)N_ * 4;
            nz0 = *(const ushort8v*)(Kz + nb);
            nz1 = *(const ushort8v*)(Kz + nb + 8);
            nh0 = *(const ushort8v*)(Kh + nb);
            nh1 = *(const ushort8v*)(Kh + nb + 8);
        }
        QUAD_MATH({ V[j] = f * V[j] + v; F[j] *= f; })
        z0 = nz0; z1 = nz1; h0v = nh0; h1v = nh1;
        base += (size_t)N_ * 4;
    }
    size_t o = ((size_t)(b * NC + c)) * H_ + hb;
    *(float4*)(Fc + o) = make_float4(F[0], F[1], F[2], F[3]);
    *(float4*)(Vc + o) = make_float4(V[0], V[1], V[2], V[3]);
}

// ---------------- scan B: serial scan over chunk aggregates; writes t=0 row ----------------
// spread over (B, H/256) blocks x 64 threads; F/V prefetched one step ahead of the chain
__global__ __launch_bounds__(64) void scanB_kernel(const float* __restrict__ h0,
                                                   const float* __restrict__ Fc,
                                                   const float* __restrict__ Vc,
                                                   float* __restrict__ Carry,
                                                   float* __restrict__ Out)
{
    const int b = blockIdx.x;
    const int h = blockIdx.y * 256 + threadIdx.x * 4;
    float cy[4];
#pragma unroll
    for (int j = 0; j < 4; j++) cy[j] = gfun(h0[(size_t)b * H_ + h + j]);
    *(float4*)(Out + (size_t)b * (T_ + 1) * H_ + h) = make_float4(cy[0], cy[1], cy[2], cy[3]);
    size_t o = ((size_t)(b * NC)) * H_ + h;
    float4 F4 = *(const float4*)(Fc + o);
    float4 V4 = *(const float4*)(Vc + o);
    for (int c = 0; c < NC; c++) {
        const size_t on = o + H_;
        float4 nF, nV;
        if (c + 1 < NC) {
            nF = *(const float4*)(Fc + on);
            nV = *(const float4*)(Vc + on);
        }
        *(float4*)(Carry + o) = make_float4(cy[0], cy[1], cy[2], cy[3]);
        cy[0] = F4.x * cy[0] + V4.x;
        cy[1] = F4.y * cy[1] + V4.y;
        cy[2] = F4.z * cy[2] + V4.z;
        cy[3] = F4.w * cy[3] + V4.w;
        F4 = nF; V4 = nV; o = on;
    }
}

// ---------------- scan C: replay chunks with incoming carry, write outputs ----------------
__global__ __launch_bounds__(256) void scanC_kernel(const unsigned short* __restrict__ Kz,
                                                    const unsigned short* __restrict__ Kh,
                                                    const float* __restrict__ Carry,
                                                    float* __restrict__ Out)
{
    const int c = blockIdx.x, b = blockIdx.y;
    const int hb = threadIdx.x * 4;
    float cy[4];
    {
        float4 c4 = *(const float4*)(Carry + ((size_t)(b * NC + c)) * H_ + hb);
        cy[0] = c4.x; cy[1] = c4.y; cy[2] = c4.z; cy[3] = c4.w;
    }
    size_t base = ((size_t)(b * (T_ / 4) + c * (TC / 4)) * N_ + hb) * 4;
    size_t ob = ((size_t)(b * (T_ + 1) + c * TC + 1)) * H_ + hb;
    ushort8v z0 = *(const ushort8v*)(Kz + base);
    ushort8v z1 = *(const ushort8v*)(Kz + base + 8);
    ushort8v h0v = *(const ushort8v*)(Kh + base);
    ushort8v h1v = *(const ushort8v*)(Kh + base + 8);
#pragma unroll 1
    for (int qq = 0; qq < TC / 4; qq++) {
        ushort8v nz0, nz1, nh0, nh1;
        if (qq + 1 < TC / 4) {
            const size_t nb = base + (size_t)N_ * 4;
            nz0 = *(const ushort8v*)(Kz + nb);
            nz1 = *(const ushort8v*)(Kz + nb + 8);
            nh0 = *(const ushort8v*)(Kh + nb);
            nh1 = *(const ushort8v*)(Kh + nb + 8);
        }
        QUAD_MATH({
            cy[j] = f * cy[j] + v;
            if (j == 3) { *(float4*)(Out + ob) = make_float4(cy[0], cy[1], cy[2], cy[3]); ob += H_; }
        })
        z0 = nz0; z1 = nz1; h0v = nh0; h1v = nh1;
        base += (size_t)N_ * 4;
    }
}

extern "C" void kernel_launch(void* const* d_in, const int* in_sizes, int n_in,
                              void* d_out, int out_size, void* d_ws, size_t ws_size,
                              hipStream_t stream)
{
    const float* x  = (const float*)d_in[0];
    const float* h0 = (const float*)d_in[1];
    const float* Wz = (const float*)d_in[2];
    const float* bz = (const float*)d_in[3];
    const float* Wh = (const float*)d_in[4];
    const float* bh = (const float*)d_in[5];
    float* out = (float*)d_out;

    char* ws = (char*)d_ws;
    unsigned short* xb  = (unsigned short*)ws; ws += (size_t)M_ * K_ * 2;   // 64 MiB
    unsigned short* wzb = (unsigned short*)ws; ws += (size_t)N_ * K_ * 2;   // 2 MiB
    unsigned short* whb = (unsigned short*)ws; ws += (size_t)N_ * K_ * 2;   // 2 MiB
    unsigned short* kz  = (unsigned short*)ws; ws += (size_t)M_ * N_ * 2;   // 64 MiB
    unsigned short* kh  = (unsigned short*)ws; ws += (size_t)M_ * N_ * 2;   // 64 MiB
    float* Fc    = (float*)ws; ws += (size_t)B_ * NC * H_ * 4;              // 4 MiB
    float* Vc    = (float*)ws; ws += (size_t)B_ * NC * H_ * 4;              // 4 MiB
    float* Carry = (float*)ws; ws += (size_t)B_ * NC * H_ * 4;              // 4 MiB

    cvt_kernel<<<2048, 256, 0, stream>>>(x, xb, M_ * K_ / 4);
    cvtw_kernel<<<dim3(128, 2), 256, 0, stream>>>(Wz, Wh, wzb, whb, N_ * K_ / 4);

    dim3 gg(M_ / 1024, N_ / 256, 2);
    gemm_kernel<<<gg, 512, 0, stream>>>(xb, wzb, whb, bz, bh, kz, kh);

    scanA_kernel<<<dim3(NC, B_), 256, 0, stream>>>(kz, kh, Fc, Vc);
    scanB_kernel<<<dim3(B_, H_ / 256), 64, 0, stream>>>(h0, Fc, Vc, Carry, out);
    scanC_kernel<<<dim3(NC, B_), 256, 0, stream>>>(kz, kh, Carry, out);
}